// Round 1
// baseline (93.011 us; speedup 1.0000x reference)
//
#include <hip/hip_runtime.h>

typedef float f4 __attribute__((ext_vector_type(4)));

#define BB    2
#define DDIM  1024
#define LSEQ  8192
#define NG    256
#define LC    128
#define TD    16      // channels per block (4 groups)
#define TL    512     // l-extent per block
#define HALO  128
#define ZW    (TL + HALO)   // 640 floats per staged row

__global__ __launch_bounds__(256) void hyena_fir_kernel(
    const float* __restrict__ x1,
    const float* __restrict__ x2,
    const float* __restrict__ v,
    const float* __restrict__ h,
    const float* __restrict__ cb,
    float* __restrict__ out)
{
    __shared__ float zbuf[TD][ZW];      // z = x2*v tile (+halo); reused to stage output
    __shared__ float ksh[TD/4][LC];     // decay filters for the 4 groups

    const int t  = threadIdx.x;
    const int d0 = blockIdx.x * TD;
    const int l0 = blockIdx.y * TL;
    const int b  = blockIdx.z;

    // --- build k[g,m] = h[g,m] * exp(-10^(2g/255) * m/127) for our 4 groups ---
    for (int i = t; i < (TD/4)*LC; i += 256) {
        const int glocal = i >> 7;
        const int m      = i & (LC-1);
        const int g      = (d0 >> 2) + glocal;
        const float dd   = __expf((float)g * (2.0f/255.0f) * 2.302585092994046f); // 10^(2g/255)
        ksh[glocal][m]   = h[g*LC + m] * __expf(-dd * (float)m * (1.0f/127.0f));
    }

    // --- stage z = x2*v for l in [l0-HALO, l0+TL), zeros before sequence start ---
    for (int idx = t; idx < TD*(ZW/4); idx += 256) {
        const int r  = idx / (ZW/4);
        const int c4 = idx - r*(ZW/4);
        const int gl = l0 - HALO + c4*4;
        const size_t rb = ((size_t)(b*DDIM + d0 + r)) * LSEQ;
        f4 z = {0.f,0.f,0.f,0.f};
        if (gl >= 0) {
            f4 a = *(const f4*)(x2 + rb + gl);
            f4 w = *(const f4*)(v  + rb + gl);
            z = a * w;
        }
        *(f4*)&zbuf[r][c4*4] = z;
    }
    __syncthreads();

    // --- FIR: each wave owns 4 rows; each lane computes 4 consecutive l's, twice ---
    const int wave = t >> 6, lane = t & 63;
    f4 res[4][2];
    for (int rr = 0; rr < 4; ++rr) {
        const int row = wave*4 + rr;
        const float* __restrict__ kk = ksh[row >> 2];
        const float* __restrict__ zb = zbuf[row];
        const float bd = cb[d0 + row];
        const size_t rbase = ((size_t)(b*DDIM + d0 + row)) * LSEQ + l0;
        for (int c = 0; c < 2; ++c) {
            const int lb = c*256 + lane*4;      // output l_local = lb..lb+3
            f4 acc = {0.f,0.f,0.f,0.f};
            f4 Bv = *(const f4*)&zb[lb + HALO]; // z[l0+lb .. +3]
            const f4 zself = Bv;
            #pragma unroll 8
            for (int mc = 0; mc < 32; ++mc) {   // taps m = 4*mc + mm
                const f4 Av = *(const f4*)&zb[lb + HALO - 4 - mc*4];
                const f4 k4 = *(const f4*)&kk[mc*4];
                acc[0] += k4[0]*Bv[0]; acc[0] += k4[1]*Av[3]; acc[0] += k4[2]*Av[2]; acc[0] += k4[3]*Av[1];
                acc[1] += k4[0]*Bv[1]; acc[1] += k4[1]*Bv[0]; acc[1] += k4[2]*Av[3]; acc[1] += k4[3]*Av[2];
                acc[2] += k4[0]*Bv[2]; acc[2] += k4[1]*Bv[1]; acc[2] += k4[2]*Bv[0]; acc[2] += k4[3]*Av[3];
                acc[3] += k4[0]*Bv[3]; acc[3] += k4[1]*Bv[2]; acc[3] += k4[2]*Bv[1]; acc[3] += k4[3]*Bv[0];
                Bv = Av;                        // sliding window: next B is current A
            }
            const f4 xv = *(const f4*)(x1 + rbase + lb);
            f4 r4;
            r4[0] = (acc[0] + zself[0]*bd) * xv[0];
            r4[1] = (acc[1] + zself[1]*bd) * xv[1];
            r4[2] = (acc[2] + zself[2]*bd) * xv[2];
            r4[3] = (acc[3] + zself[3]*bd) * xv[3];
            res[rr][c] = r4;
        }
    }
    __syncthreads();

    // --- stage results back into zbuf (rows reused, stride ZW keeps 16B alignment) ---
    for (int rr = 0; rr < 4; ++rr) {
        const int row = wave*4 + rr;
        for (int c = 0; c < 2; ++c) {
            const int lb = c*256 + lane*4;
            *(f4*)&zbuf[row][lb] = res[rr][c];
        }
    }
    __syncthreads();

    // --- transposed write-out: full 64B lines at out[b, l0+l, d0..d0+15] ---
    const int q = t & 3, lidx = t >> 2;
    for (int i = 0; i < 8; ++i) {
        const int l = lidx + i*64;
        f4 o;
        o[0] = zbuf[q*4+0][l];
        o[1] = zbuf[q*4+1][l];
        o[2] = zbuf[q*4+2][l];
        o[3] = zbuf[q*4+3][l];
        *(f4*)(out + ((size_t)b*LSEQ + l0 + l)*DDIM + d0 + q*4) = o;
    }
}

extern "C" void kernel_launch(void* const* d_in, const int* in_sizes, int n_in,
                              void* d_out, int out_size, void* d_ws, size_t ws_size,
                              hipStream_t stream) {
    const float* x1 = (const float*)d_in[0];
    const float* x2 = (const float*)d_in[1];
    const float* v  = (const float*)d_in[2];
    const float* h  = (const float*)d_in[3];
    const float* cb = (const float*)d_in[4];
    float* out = (float*)d_out;
    dim3 grid(DDIM/TD, LSEQ/TL, BB);
    hipLaunchKernelGGL(hyena_fir_kernel, grid, dim3(256), 0, stream,
                       x1, x2, v, h, cb, out);
}